// Round 11
// baseline (257.116 us; speedup 1.0000x reference)
//
#include <hip/hip_runtime.h>
#include <hip/hip_cooperative_groups.h>
#include <hip/hip_bf16.h>
#include <stdint.h>

namespace cg = cooperative_groups;

#define B 16
#define NN 2048
#define DIM 256
#define SZ 16384
#define TOPK 50

// ws layout: psum [256][64]f4 at f4-idx 0 (float 0), psumsq at f4-idx 16384
// (float 65536), ds floats at OFF_DS
#define WS_PSUMSQ_F 65536
#define OFF_DS      131072

// dynamic LDS layout (bytes):
//   [0, 131072)        x slice: float4[8192]
//   [131072, 149504)   scratch: red_s/red_q | lm/ls (8-batch half) | TkSmem
//   [149504, 151552)   mb_sh[256], sb_sh[256]
#define LDS_TOTAL 151552
#define SCRATCH_OFF 131072
#define MBSB_OFF 149504

struct TkSmem {
    float wmn[16], wmx[16];
    int hist[256], hist2[256];
    float sh_lo, sh_sc;
    int sh_T, sh_below, sh_T2, sh_cnt;
    unsigned long long candK[512];
    float topd[TOPK];
    int topi[TOPK];
    float wgt[TOPK];
    float mgp[2][256], sgp[2][256];
    float shA[256], shC[256];
};

#define RS_STEP(half)                                                   \
    {                                                                   \
        bool hi = (sub & half) != 0;                                    \
        _Pragma("unroll")                                               \
        for (int j = 0; j < half; j++) {                                \
            float send = hi ? am[j] : am[j + half];                     \
            float keep = hi ? am[j + half] : am[j];                     \
            am[j] = keep + __shfl_xor(send, half, 16);                  \
            send = hi ? as[j] : as[j + half];                           \
            keep = hi ? as[j + half] : as[j];                           \
            as[j] = keep + __shfl_xor(send, half, 16);                  \
        }                                                               \
    }

extern __shared__ __align__(16) unsigned char dyn_lds[];

__global__ void __launch_bounds__(1024, 1)
k_all(const float* __restrict__ x,
      const float* __restrict__ means,
      const float* __restrict__ stds,
      const float* __restrict__ t1p,
      const float* __restrict__ t2p,
      float* __restrict__ ws,
      float* __restrict__ out) {
    cg::grid_group grid = cg::this_grid();
    int tid = threadIdx.x, bid = blockIdx.x;
    int batch = bid >> 4;
    int lane = tid & 63, wid = tid >> 6;

    float4* lds_x = (float4*)dyn_lds;                      // 8192 f4
    unsigned char* scratch = dyn_lds + SCRATCH_OFF;        // 18432 B
    float* mb_sh = (float*)(dyn_lds + MBSB_OFF);           // [256]
    float* sb_sh = mb_sh + 256;                            // [256]
    float4* wsp4 = (float4*)ws;

    // ================= phase A: x -> LDS + partial stats =================
    {
        const float4* x4 = (const float4*)x + (size_t)bid * 8192;
        float4 s = {0.f, 0.f, 0.f, 0.f}, q = {0.f, 0.f, 0.f, 0.f};
#pragma unroll
        for (int j = 0; j < 8; j++) {
            float4 v = x4[j * 1024 + tid];
            lds_x[j * 1024 + tid] = v;
            s.x += v.x; s.y += v.y; s.z += v.z; s.w += v.w;
            q.x += v.x * v.x; q.y += v.y * v.y; q.z += v.z * v.z; q.w += v.w * v.w;
        }
        // tree-reduce over the 16 waves (w = wid, col = lane)
        float4* red_s = (float4*)scratch;        // up to [8][64]
        float4* red_q = red_s + 512;             // up to [8][64]
#pragma unroll
        for (int off = 8; off >= 1; off >>= 1) {
            if (wid >= off && wid < 2 * off) {
                red_s[(wid - off) * 64 + lane] = s;
                red_q[(wid - off) * 64 + lane] = q;
            }
            __syncthreads();
            if (wid < off) {
                float4 a = red_s[wid * 64 + lane], b2 = red_q[wid * 64 + lane];
                s.x += a.x; s.y += a.y; s.z += a.z; s.w += a.w;
                q.x += b2.x; q.y += b2.y; q.z += b2.z; q.w += b2.w;
            }
            __syncthreads();
        }
        if (wid == 0) {
            wsp4[bid * 64 + lane] = s;                    // psum
            wsp4[16384 + bid * 64 + lane] = q;            // psumsq
        }
    }
    grid.sync();

    // ======= phase B: redundant finalize (two 8-batch halves) + dist =======
    {
        float4* lm = (float4*)scratch;       // [8][64] f4 mean
        float4* ls = lm + 512;               // [8][64] f4 std
        int sub = lane & 15, eg = lane >> 4;
        int e = bid * 64 + wid * 4 + eg;
        const float4* mrow = (const float4*)means + (size_t)e * 64;
        const float4* srow = (const float4*)stds + (size_t)e * 64;
        float4 m[4], s[4];
#pragma unroll
        for (int k = 0; k < 4; k++) {
            m[k] = mrow[k * 16 + sub];
            s[k] = srow[k * 16 + sub];
        }
        float am[16], as[16];
#pragma unroll
        for (int h = 0; h < 2; h++) {
            if (tid < 512) {
                int bl = tid >> 6, d4 = tid & 63;
                int bb = h * 8 + bl;
                float4 S = {0.f, 0.f, 0.f, 0.f}, Q = {0.f, 0.f, 0.f, 0.f};
#pragma unroll
                for (int c = 0; c < 16; c++) {
                    float4 a = wsp4[(bb * 16 + c) * 64 + d4];
                    float4 b2 = wsp4[16384 + (bb * 16 + c) * 64 + d4];
                    S.x += a.x; S.y += a.y; S.z += a.z; S.w += a.w;
                    Q.x += b2.x; Q.y += b2.y; Q.z += b2.z; Q.w += b2.w;
                }
                const float inv = 1.f / NN;
                float4 M, D;
                M.x = S.x * inv; M.y = S.y * inv; M.z = S.z * inv; M.w = S.w * inv;
                D.x = sqrtf(fmaxf(Q.x * inv - M.x * M.x, 0.f));
                D.y = sqrtf(fmaxf(Q.y * inv - M.y * M.y, 0.f));
                D.z = sqrtf(fmaxf(Q.z * inv - M.z * M.z, 0.f));
                D.w = sqrtf(fmaxf(Q.w * inv - M.w * M.w, 0.f));
                lm[bl * 64 + d4] = M;
                ls[bl * 64 + d4] = D;
            }
            __syncthreads();
#pragma unroll
            for (int bb = 0; bb < 8; bb++) {
                float accm = 0.f, accs = 0.f;
#pragma unroll
                for (int k = 0; k < 4; k++) {
                    float4 qv = lm[bb * 64 + k * 16 + sub];
                    float dx = m[k].x - qv.x, dy = m[k].y - qv.y;
                    float dz = m[k].z - qv.z, dw = m[k].w - qv.w;
                    accm += dx * dx + dy * dy + dz * dz + dw * dw;
                    qv = ls[bb * 64 + k * 16 + sub];
                    dx = s[k].x - qv.x; dy = s[k].y - qv.y;
                    dz = s[k].z - qv.z; dw = s[k].w - qv.w;
                    accs += dx * dx + dy * dy + dz * dz + dw * dw;
                }
                am[h * 8 + bb] = accm;
                as[h * 8 + bb] = accs;
            }
            __syncthreads();
        }
        RS_STEP(8)
        RS_STEP(4)
        RS_STEP(2)
        RS_STEP(1)
        ws[OFF_DS + sub * SZ + e] = sqrtf(am[0]) + sqrtf(as[0]);

        // own-batch mean/std -> small persistent LDS (survives TkSmem reuse)
        if (tid < 256) {
            float sfv = 0.f, qfv = 0.f;
#pragma unroll
            for (int c = 0; c < 16; c++) {
                sfv += ws[(batch * 16 + c) * 256 + tid];
                qfv += ws[WS_PSUMSQ_F + (batch * 16 + c) * 256 + tid];
            }
            float mean = sfv * (1.f / NN);
            float sd = sqrtf(fmaxf(qfv * (1.f / NN) - mean * mean, 0.f));
            mb_sh[tid] = mean;
            sb_sh[tid] = sd;
        }
    }
    grid.sync();

    // ================= phase C: top-k + goal + apply =================
    {
        TkSmem* S = (TkSmem*)scratch;
        const float4* ds4 = (const float4*)(ws + OFF_DS + batch * SZ);

        float v[16];
        {
            float4 t0 = ds4[tid], t1_ = ds4[tid + 1024];
            float4 t2_ = ds4[tid + 2048], t3 = ds4[tid + 3072];
            v[0] = t0.x; v[1] = t0.y; v[2] = t0.z; v[3] = t0.w;
            v[4] = t1_.x; v[5] = t1_.y; v[6] = t1_.z; v[7] = t1_.w;
            v[8] = t2_.x; v[9] = t2_.y; v[10] = t2_.z; v[11] = t2_.w;
            v[12] = t3.x; v[13] = t3.y; v[14] = t3.z; v[15] = t3.w;
        }
        float mn = v[0], mx = v[0];
#pragma unroll
        for (int i = 1; i < 16; i++) { mn = fminf(mn, v[i]); mx = fmaxf(mx, v[i]); }
#pragma unroll
        for (int off = 32; off > 0; off >>= 1) {
            mn = fminf(mn, __shfl_xor(mn, off, 64));
            mx = fmaxf(mx, __shfl_xor(mx, off, 64));
        }
        if (lane == 0) { S->wmn[wid] = mn; S->wmx[wid] = mx; }
        if (tid < 256) { S->hist[tid] = 0; S->hist2[tid] = 0; }
        if (tid == 0) S->sh_cnt = 0;
        __syncthreads();
        if (tid == 0) {
            float l = S->wmn[0], h = S->wmx[0];
#pragma unroll
            for (int i = 1; i < 16; i++) { l = fminf(l, S->wmn[i]); h = fmaxf(h, S->wmx[i]); }
            S->sh_lo = l;
            S->sh_sc = 255.0f / fmaxf(h - l, 1e-20f);
        }
        __syncthreads();
        float lo = S->sh_lo, sc = S->sh_sc;

        int bn[16];
#pragma unroll
        for (int i = 0; i < 16; i++) {
            bn[i] = min(max((int)((v[i] - lo) * sc), 0), 255);
            atomicAdd(&S->hist[bn[i]], 1);
        }
        __syncthreads();
        if (wid == 0) {
            int a0 = S->hist[4 * lane], a1 = S->hist[4 * lane + 1];
            int a2 = S->hist[4 * lane + 2], a3 = S->hist[4 * lane + 3];
            a1 += a0; a2 += a1; a3 += a2;
            int tot = a3, run = tot;
#pragma unroll
            for (int off = 1; off < 64; off <<= 1) {
                int o = __shfl_up(run, off, 64);
                if (lane >= off) run += o;
            }
            int excl = run - tot;
            int c0 = a0 + excl, c1 = a1 + excl, c2 = a2 + excl, c3 = a3 + excl;
            int cc[4] = {c0, c1, c2, c3};
            int pp[4] = {excl, c0, c1, c2};
#pragma unroll
            for (int j = 0; j < 4; j++)
                if (cc[j] >= TOPK && pp[j] < TOPK) { S->sh_T = 4 * lane + j; S->sh_below = pp[j]; }
        }
        __syncthreads();
        int T = S->sh_T, below = S->sh_below;

        float flo = lo + (float)T / sc;
        float fsc = sc * 255.0f;
#pragma unroll
        for (int i = 0; i < 16; i++) {
            if (bn[i] == T) {
                int fbn = min(max((int)((v[i] - flo) * fsc), 0), 255);
                atomicAdd(&S->hist2[fbn], 1);
            }
        }
        __syncthreads();
        int need = TOPK - below;
        if (wid == 0) {
            int a0 = S->hist2[4 * lane], a1 = S->hist2[4 * lane + 1];
            int a2 = S->hist2[4 * lane + 2], a3 = S->hist2[4 * lane + 3];
            a1 += a0; a2 += a1; a3 += a2;
            int tot = a3, run = tot;
#pragma unroll
            for (int off = 1; off < 64; off <<= 1) {
                int o = __shfl_up(run, off, 64);
                if (lane >= off) run += o;
            }
            int excl = run - tot;
            int c0 = a0 + excl, c1 = a1 + excl, c2 = a2 + excl, c3 = a3 + excl;
            int cc[4] = {c0, c1, c2, c3};
            int pp[4] = {excl, c0, c1, c2};
#pragma unroll
            for (int j = 0; j < 4; j++)
                if (cc[j] >= need && pp[j] < need) S->sh_T2 = 4 * lane + j;
        }
        __syncthreads();
        int T2 = S->sh_T2;

#pragma unroll
        for (int i = 0; i < 16; i++) {
            bool take = bn[i] < T;
            if (bn[i] == T) {
                int fbn = min(max((int)((v[i] - flo) * fsc), 0), 255);
                take = (fbn <= T2);
            }
            if (take) {
                int p = atomicAdd(&S->sh_cnt, 1);
                if (p < 512) {
                    int idx = 4 * (tid + (i >> 2) * 1024) + (i & 3);
                    S->candK[p] = ((unsigned long long)__float_as_uint(v[i]) << 32) | (unsigned int)idx;
                }
            }
        }
        __syncthreads();
        int cnt = min(S->sh_cnt, 512);

        for (int p = tid; p < cnt; p += 1024) {
            unsigned long long kp = S->candK[p];
            int rank = 0;
            for (int q = 0; q < cnt; q++) rank += (S->candK[q] < kp) ? 1 : 0;
            if (rank < TOPK) {
                S->topd[rank] = __uint_as_float((unsigned int)(kp >> 32));
                S->topi[rank] = (int)(kp & 0xffffffffu);
            }
        }
        __syncthreads();

        float t1 = t1p[0], t2v = t2p[0];
        if (wid == 0) {
            float sv = (lane < TOPK) ? expf(-t1 * S->topd[lane]) : -1e30f;
            float m = sv;
#pragma unroll
            for (int off = 32; off > 0; off >>= 1) m = fmaxf(m, __shfl_xor(m, off, 64));
            float e = (lane < TOPK) ? expf(sv - m) : 0.f;
            float sum = e;
#pragma unroll
            for (int off = 32; off > 0; off >>= 1) sum += __shfl_xor(sum, off, 64);
            if (lane < TOPK) S->wgt[lane] = e / sum;
        }
        __syncthreads();

        if (tid < 512) {
            int d = tid & 255, qd = tid >> 8;  // 2 groups of 256
            float mg = 0.f, sg = 0.f;
            for (int r = qd; r < TOPK; r += 2) {
                float w = S->wgt[r];
                int idx = S->topi[r];
                mg += w * means[(size_t)idx * DIM + d];
                sg += w * stds[(size_t)idx * DIM + d];
            }
            S->mgp[qd][d] = mg;
            S->sgp[qd][d] = sg;
        }
        __syncthreads();
        if (tid < 256) {
            float MG = S->mgp[0][tid] + S->mgp[1][tid];
            float SG = S->sgp[0][tid] + S->sgp[1][tid];
            float mean = mb_sh[tid];
            float sd = sb_sh[tid];
            float lerp = 1.f / (1.f + expf(-t2v));
            float mf = lerp * MG + (1.f - lerp) * mean;
            float sf = lerp * SG + (1.f - lerp) * sd;
            float A = sf / sd;
            float C = mf - A * mean;
            S->shA[tid] = A;
            S->shC[tid] = C;
        }
        __syncthreads();

        float4* oo = (float4*)out + (size_t)bid * 8192;
        const float4* la = (const float4*)S->shA;
        const float4* lc = (const float4*)S->shC;
        int d4 = tid & 63;
        float4 a = la[d4], c = lc[d4];
#pragma unroll
        for (int i = 0; i < 8; i++) {
            float4 xv = lds_x[i * 1024 + tid];
            float4 o;
            o.x = fmaf(a.x, xv.x, c.x);
            o.y = fmaf(a.y, xv.y, c.y);
            o.z = fmaf(a.z, xv.z, c.z);
            o.w = fmaf(a.w, xv.w, c.w);
            oo[i * 1024 + tid] = o;
        }
    }
}

extern "C" void kernel_launch(void* const* d_in, const int* in_sizes, int n_in,
                              void* d_out, int out_size, void* d_ws, size_t ws_size,
                              hipStream_t stream) {
    const float* x = (const float*)d_in[0];
    const float* means = (const float*)d_in[1];
    const float* stds = (const float*)d_in[2];
    const float* t1 = (const float*)d_in[3];
    const float* t2 = (const float*)d_in[4];
    float* out = (float*)d_out;
    float* ws = (float*)d_ws;

    hipFuncSetAttribute((const void*)k_all,
                        hipFuncAttributeMaxDynamicSharedMemorySize, LDS_TOTAL);
    void* args[] = {&x, &means, &stds, &t1, &t2, &ws, &out};
    hipLaunchCooperativeKernel((const void*)k_all, dim3(256), dim3(1024),
                               args, LDS_TOTAL, stream);
}

// Round 13
// 53.179 us; speedup vs baseline: 4.8349x; 4.8349x over previous
//
#include <hip/hip_runtime.h>
#include <hip/hip_bf16.h>
#include <stdint.h>

#define B 16
#define NN 2048
#define DIM 256
#define SZ 16384
#define TOPK 50
#define NCHUNK 16
#define CROWS 128   // rows per chunk

// ws float offsets (no sync area, no atomics anywhere)
#define OFF_PSUM   0        // [16][16][256]
#define OFF_PSUMSQ 65536    // [16][16][256]
#define OFF_MEANB  131072   // [16][256]
#define OFF_STDB   135168   // [16][256]
#define OFF_DS     139264   // [16][16384]

// ---------- kernel 1: pure partial stats (no sync, no atomics) ----------
__global__ __launch_bounds__(512) void k_partial(const float* __restrict__ x,
                                                 float* __restrict__ ws) {
    int bid = blockIdx.x;           // 256 blocks
    int b = bid >> 4, c = bid & 15; // batch, 128-row chunk
    int t = threadIdx.x;
    int w = t >> 6, col = t & 63;   // 8 row-phases x 64 cols
    const float4* p = (const float4*)x + ((size_t)(b * NN + c * CROWS + w)) * 64 + col;
    float4 s = {0.f, 0.f, 0.f, 0.f}, q = {0.f, 0.f, 0.f, 0.f};
#pragma unroll 4
    for (int j = 0; j < 16; j++) {  // rows w, w+8, ..., w+120
        float4 v = p[(size_t)j * 512];
        s.x += v.x; s.y += v.y; s.z += v.z; s.w += v.w;
        q.x += v.x * v.x; q.y += v.y * v.y; q.z += v.z * v.z; q.w += v.w * v.w;
    }
    __shared__ float4 ss[8][64], qq[8][64];
    ss[w][col] = s; qq[w][col] = q;
    __syncthreads();
    if (t < 64) {
        float4 S = ss[0][t], Q = qq[0][t];
#pragma unroll
        for (int r = 1; r < 8; r++) {
            float4 a = ss[r][t], b2 = qq[r][t];
            S.x += a.x; S.y += a.y; S.z += a.z; S.w += a.w;
            Q.x += b2.x; Q.y += b2.y; Q.z += b2.z; Q.w += b2.w;
        }
        ((float4*)(ws + OFF_PSUM))[(b * NCHUNK + c) * 64 + t] = S;
        ((float4*)(ws + OFF_PSUMSQ))[(b * NCHUNK + c) * 64 + t] = Q;
    }
}

// ---------- kernel 2: redundant stats finalize + distances ----------
#define RS_STEP(half)                                                   \
    {                                                                   \
        bool hi = (sub & half) != 0;                                    \
        _Pragma("unroll")                                               \
        for (int j = 0; j < half; j++) {                                \
            float send = hi ? am[j] : am[j + half];                     \
            float keep = hi ? am[j + half] : am[j];                     \
            am[j] = keep + __shfl_xor(send, half, 16);                  \
            send = hi ? as[j] : as[j + half];                           \
            keep = hi ? as[j + half] : as[j];                           \
            as[j] = keep + __shfl_xor(send, half, 16);                  \
        }                                                               \
    }

__global__ __launch_bounds__(1024) void k_dist(const float* __restrict__ means,
                                               const float* __restrict__ stds,
                                               float* __restrict__ ws) {
    __shared__ float4 lm[16 * 64], ls[16 * 64];  // [batch][64] f4 mean/std
    int tid = threadIdx.x, bid = blockIdx.x;     // 256 blocks x 1024 thr
    int lane = tid & 63, wid = tid >> 6;
    int sub = lane & 15, eg = lane >> 4;
    int e = bid * 64 + wid * 4 + eg;

    // T14: issue the big means/stds register loads FIRST so their HBM fetch
    // overlaps the psum-finalize compute below.
    const float4* mrow = (const float4*)means + (size_t)e * 64;
    const float4* srow = (const float4*)stds + (size_t)e * 64;
    float4 m[4], s[4];
#pragma unroll
    for (int k = 0; k < 4; k++) {
        m[k] = mrow[k * 16 + sub];
        s[k] = srow[k * 16 + sub];
    }

    // phase 0: redundant per-block stats finalize (deterministic, L2-hot psums)
    {
        int b = tid >> 6, d4 = tid & 63;  // (batch, dim-quad)
        const float4* ps = (const float4*)(ws + OFF_PSUM) + (b * NCHUNK) * 64 + d4;
        const float4* pq = (const float4*)(ws + OFF_PSUMSQ) + (b * NCHUNK) * 64 + d4;
        float4 S = {0.f, 0.f, 0.f, 0.f}, Q = {0.f, 0.f, 0.f, 0.f};
#pragma unroll
        for (int c = 0; c < NCHUNK; c++) {
            float4 a = ps[c * 64], b2 = pq[c * 64];
            S.x += a.x; S.y += a.y; S.z += a.z; S.w += a.w;
            Q.x += b2.x; Q.y += b2.y; Q.z += b2.z; Q.w += b2.w;
        }
        const float inv = 1.f / NN;
        float4 M, D;
        M.x = S.x * inv; M.y = S.y * inv; M.z = S.z * inv; M.w = S.w * inv;
        D.x = sqrtf(fmaxf(Q.x * inv - M.x * M.x, 0.f));
        D.y = sqrtf(fmaxf(Q.y * inv - M.y * M.y, 0.f));
        D.z = sqrtf(fmaxf(Q.z * inv - M.z * M.z, 0.f));
        D.w = sqrtf(fmaxf(Q.w * inv - M.w * M.w, 0.f));
        lm[b * 64 + d4] = M;
        ls[b * 64 + d4] = D;
        // publish for k_applytopk (identical values from every block: benign)
        ((float4*)(ws + OFF_MEANB))[b * 64 + d4] = M;
        ((float4*)(ws + OFF_STDB))[b * 64 + d4] = D;
    }
    __syncthreads();

    // phase 1: distances, 64 entries per block (4 per wave)
    float am[16], as[16];
#pragma unroll
    for (int b = 0; b < 16; b++) {
        float accm = 0.f, accs = 0.f;
#pragma unroll
        for (int k = 0; k < 4; k++) {
            float4 q = lm[b * 64 + k * 16 + sub];
            float dx = m[k].x - q.x, dy = m[k].y - q.y;
            float dz = m[k].z - q.z, dw = m[k].w - q.w;
            accm += dx * dx + dy * dy + dz * dz + dw * dw;
            q = ls[b * 64 + k * 16 + sub];
            dx = s[k].x - q.x; dy = s[k].y - q.y;
            dz = s[k].z - q.z; dw = s[k].w - q.w;
            accs += dx * dx + dy * dy + dz * dz + dw * dw;
        }
        am[b] = accm; as[b] = accs;
    }
    RS_STEP(8)
    RS_STEP(4)
    RS_STEP(2)
    RS_STEP(1)
    ws[OFF_DS + sub * SZ + e] = sqrtf(am[0]) + sqrtf(as[0]);
}

// ---------- kernel 3: per-block redundant top-k/goal + apply (x prefetched) ----------
struct TkSmem {
    float wmn[16], wmx[16];
    int hist[256], hist2[256];
    float sh_lo, sh_sc;
    int sh_T, sh_below, sh_T2, sh_cnt;
    unsigned long long candK[512];
    float topd[TOPK];
    int topi[TOPK];
    float wgt[TOPK];
    float mgp[4][256], sgp[4][256];
    float shA[256], shC[256];
};

__global__ __launch_bounds__(1024) void k_applytopk(const float* __restrict__ x,
                                                    const float* __restrict__ means,
                                                    const float* __restrict__ stds,
                                                    const float* __restrict__ t1p,
                                                    const float* __restrict__ t2p,
                                                    const float* __restrict__ ws,
                                                    float* __restrict__ out) {
    __shared__ TkSmem S;
    int tid = threadIdx.x, bid = blockIdx.x;
    int batch = bid >> 4;
    int lane = tid & 63, wid = tid >> 6;
    const float4* ds4 = (const float4*)(ws + OFF_DS + batch * SZ);
    const float4* xx = (const float4*)x + (size_t)bid * 8192;

    // ds loads first, then prefetch x slice to registers (T14): x HBM fetch
    // overlaps the whole top-k phase.
    float v[16];
    float4 t0 = ds4[tid], t1_ = ds4[tid + 1024], t2_ = ds4[tid + 2048], t3 = ds4[tid + 3072];
    float4 xv[8];
#pragma unroll
    for (int i = 0; i < 8; i++) xv[i] = xx[i * 1024 + tid];
    v[0] = t0.x; v[1] = t0.y; v[2] = t0.z; v[3] = t0.w;
    v[4] = t1_.x; v[5] = t1_.y; v[6] = t1_.z; v[7] = t1_.w;
    v[8] = t2_.x; v[9] = t2_.y; v[10] = t2_.z; v[11] = t2_.w;
    v[12] = t3.x; v[13] = t3.y; v[14] = t3.z; v[15] = t3.w;

    float mn = v[0], mx = v[0];
#pragma unroll
    for (int i = 1; i < 16; i++) { mn = fminf(mn, v[i]); mx = fmaxf(mx, v[i]); }
#pragma unroll
    for (int off = 32; off > 0; off >>= 1) {
        mn = fminf(mn, __shfl_xor(mn, off, 64));
        mx = fmaxf(mx, __shfl_xor(mx, off, 64));
    }
    if (lane == 0) { S.wmn[wid] = mn; S.wmx[wid] = mx; }
    if (tid < 256) { S.hist[tid] = 0; S.hist2[tid] = 0; }
    if (tid == 0) S.sh_cnt = 0;
    __syncthreads();
    if (tid == 0) {
        float l = S.wmn[0], h = S.wmx[0];
#pragma unroll
        for (int i = 1; i < 16; i++) { l = fminf(l, S.wmn[i]); h = fmaxf(h, S.wmx[i]); }
        S.sh_lo = l;
        S.sh_sc = 255.0f / fmaxf(h - l, 1e-20f);
    }
    __syncthreads();
    float lo = S.sh_lo, sc = S.sh_sc;

    int bn[16];
#pragma unroll
    for (int i = 0; i < 16; i++) {
        bn[i] = min(max((int)((v[i] - lo) * sc), 0), 255);
        atomicAdd(&S.hist[bn[i]], 1);
    }
    __syncthreads();
    if (wid == 0) {
        int a0 = S.hist[4 * lane], a1 = S.hist[4 * lane + 1];
        int a2 = S.hist[4 * lane + 2], a3 = S.hist[4 * lane + 3];
        a1 += a0; a2 += a1; a3 += a2;
        int tot = a3, run = tot;
#pragma unroll
        for (int off = 1; off < 64; off <<= 1) {
            int o = __shfl_up(run, off, 64);
            if (lane >= off) run += o;
        }
        int excl = run - tot;
        int c0 = a0 + excl, c1 = a1 + excl, c2 = a2 + excl, c3 = a3 + excl;
        int cc[4] = {c0, c1, c2, c3};
        int pp[4] = {excl, c0, c1, c2};
#pragma unroll
        for (int j = 0; j < 4; j++)
            if (cc[j] >= TOPK && pp[j] < TOPK) { S.sh_T = 4 * lane + j; S.sh_below = pp[j]; }
    }
    __syncthreads();
    int T = S.sh_T, below = S.sh_below;

    float flo = lo + (float)T / sc;
    float fsc = sc * 255.0f;
#pragma unroll
    for (int i = 0; i < 16; i++) {
        if (bn[i] == T) {
            int fbn = min(max((int)((v[i] - flo) * fsc), 0), 255);
            atomicAdd(&S.hist2[fbn], 1);
        }
    }
    __syncthreads();
    int need = TOPK - below;
    if (wid == 0) {
        int a0 = S.hist2[4 * lane], a1 = S.hist2[4 * lane + 1];
        int a2 = S.hist2[4 * lane + 2], a3 = S.hist2[4 * lane + 3];
        a1 += a0; a2 += a1; a3 += a2;
        int tot = a3, run = tot;
#pragma unroll
        for (int off = 1; off < 64; off <<= 1) {
            int o = __shfl_up(run, off, 64);
            if (lane >= off) run += o;
        }
        int excl = run - tot;
        int c0 = a0 + excl, c1 = a1 + excl, c2 = a2 + excl, c3 = a3 + excl;
        int cc[4] = {c0, c1, c2, c3};
        int pp[4] = {excl, c0, c1, c2};
#pragma unroll
        for (int j = 0; j < 4; j++)
            if (cc[j] >= need && pp[j] < need) S.sh_T2 = 4 * lane + j;
    }
    __syncthreads();
    int T2 = S.sh_T2;

#pragma unroll
    for (int i = 0; i < 16; i++) {
        bool take = bn[i] < T;
        if (bn[i] == T) {
            int fbn = min(max((int)((v[i] - flo) * fsc), 0), 255);
            take = (fbn <= T2);
        }
        if (take) {
            int p = atomicAdd(&S.sh_cnt, 1);
            if (p < 512) {
                int idx = 4 * (tid + (i >> 2) * 1024) + (i & 3);
                S.candK[p] = ((unsigned long long)__float_as_uint(v[i]) << 32) | (unsigned int)idx;
            }
        }
    }
    __syncthreads();
    int cnt = min(S.sh_cnt, 512);

    // exact rank-count selection (rank invariant to candK fill order)
    for (int p = tid; p < cnt; p += 1024) {
        unsigned long long kp = S.candK[p];
        int rank = 0;
        for (int q = 0; q < cnt; q++) rank += (S.candK[q] < kp) ? 1 : 0;
        if (rank < TOPK) {
            S.topd[rank] = __uint_as_float((unsigned int)(kp >> 32));
            S.topi[rank] = (int)(kp & 0xffffffffu);
        }
    }
    __syncthreads();

    // softmax(exp(-t1*d)) — exact double-exponential semantics
    float t1 = t1p[0], t2v = t2p[0];
    if (wid == 0) {
        float sv = (lane < TOPK) ? expf(-t1 * S.topd[lane]) : -1e30f;
        float m = sv;
#pragma unroll
        for (int off = 32; off > 0; off >>= 1) m = fmaxf(m, __shfl_xor(m, off, 64));
        float e = (lane < TOPK) ? expf(sv - m) : 0.f;
        float sum = e;
#pragma unroll
        for (int off = 32; off > 0; off >>= 1) sum += __shfl_xor(sum, off, 64);
        if (lane < TOPK) S.wgt[lane] = e / sum;
    }
    __syncthreads();

    int d = tid & 255, qd = tid >> 8;
    float mg = 0.f, sg = 0.f;
    for (int r = qd; r < TOPK; r += 4) {
        float w = S.wgt[r];
        int idx = S.topi[r];
        mg += w * means[(size_t)idx * DIM + d];
        sg += w * stds[(size_t)idx * DIM + d];
    }
    S.mgp[qd][d] = mg; S.sgp[qd][d] = sg;
    __syncthreads();
    if (tid < 256) {
        float MG = S.mgp[0][tid] + S.mgp[1][tid] + S.mgp[2][tid] + S.mgp[3][tid];
        float SG = S.sgp[0][tid] + S.sgp[1][tid] + S.sgp[2][tid] + S.sgp[3][tid];
        float mean = ws[OFF_MEANB + batch * DIM + tid];
        float sd = ws[OFF_STDB + batch * DIM + tid];
        float lerp = 1.f / (1.f + expf(-t2v));
        float mf = lerp * MG + (1.f - lerp) * mean;
        float sf = lerp * SG + (1.f - lerp) * sd;
        float A = sf / sd;
        float C = mf - A * mean;
        S.shA[tid] = A;
        S.shC[tid] = C;
    }
    __syncthreads();

    // apply from registers (x already resident)
    float4* oo = (float4*)out + (size_t)bid * 8192;
    const float4* la = (const float4*)S.shA;
    const float4* lc = (const float4*)S.shC;
#pragma unroll
    for (int i = 0; i < 8; i++) {
        int f4 = i * 1024 + tid;
        int d4 = f4 & 63;
        float4 a = la[d4], c = lc[d4];
        float4 o;
        o.x = fmaf(a.x, xv[i].x, c.x);
        o.y = fmaf(a.y, xv[i].y, c.y);
        o.z = fmaf(a.z, xv[i].z, c.z);
        o.w = fmaf(a.w, xv[i].w, c.w);
        oo[f4] = o;
    }
}

extern "C" void kernel_launch(void* const* d_in, const int* in_sizes, int n_in,
                              void* d_out, int out_size, void* d_ws, size_t ws_size,
                              hipStream_t stream) {
    const float* x = (const float*)d_in[0];
    const float* means = (const float*)d_in[1];
    const float* stds = (const float*)d_in[2];
    const float* t1 = (const float*)d_in[3];
    const float* t2 = (const float*)d_in[4];
    float* out = (float*)d_out;
    float* ws = (float*)d_ws;

    k_partial<<<B * NCHUNK, 512, 0, stream>>>(x, ws);
    k_dist<<<SZ / 64, 1024, 0, stream>>>(means, stds, ws);
    k_applytopk<<<256, 1024, 0, stream>>>(x, means, stds, t1, t2, ws, out);
}

// Round 15
// 49.375 us; speedup vs baseline: 5.2074x; 1.0770x over previous
//
#include <hip/hip_runtime.h>
#include <hip/hip_bf16.h>
#include <stdint.h>

#define B 16
#define NN 2048
#define DIM 256
#define SZ 16384
#define TOPK 50
#define NCHUNK 16
#define CROWS 128   // rows per chunk

// ws float offsets (no sync area, no atomics anywhere)
#define OFF_PSUM   0        // [16][16][256]
#define OFF_PSUMSQ 65536    // [16][16][256]
#define OFF_MEANB  131072   // [16][256]
#define OFF_STDB   135168   // [16][256]
#define OFF_DS     139264   // [16][16384]

typedef float f4v __attribute__((ext_vector_type(4)));  // native vec for nt-store

// ---------- kernel 1: pure partial stats (no sync, no atomics) ----------
__global__ __launch_bounds__(512) void k_partial(const float* __restrict__ x,
                                                 float* __restrict__ ws) {
    int bid = blockIdx.x;           // 256 blocks
    int b = bid >> 4, c = bid & 15; // batch, 128-row chunk
    int t = threadIdx.x;
    int w = t >> 6, col = t & 63;   // 8 row-phases x 64 cols
    const float4* p = (const float4*)x + ((size_t)(b * NN + c * CROWS + w)) * 64 + col;
    float4 s = {0.f, 0.f, 0.f, 0.f}, q = {0.f, 0.f, 0.f, 0.f};
#pragma unroll 8
    for (int j = 0; j < 16; j++) {  // rows w, w+8, ..., w+120
        float4 v = p[(size_t)j * 512];
        s.x += v.x; s.y += v.y; s.z += v.z; s.w += v.w;
        q.x += v.x * v.x; q.y += v.y * v.y; q.z += v.z * v.z; q.w += v.w * v.w;
    }
    __shared__ float4 ss[8][64], qq[8][64];
    ss[w][col] = s; qq[w][col] = q;
    __syncthreads();
    if (t < 64) {
        float4 S = ss[0][t], Q = qq[0][t];
#pragma unroll
        for (int r = 1; r < 8; r++) {
            float4 a = ss[r][t], b2 = qq[r][t];
            S.x += a.x; S.y += a.y; S.z += a.z; S.w += a.w;
            Q.x += b2.x; Q.y += b2.y; Q.z += b2.z; Q.w += b2.w;
        }
        ((float4*)(ws + OFF_PSUM))[(b * NCHUNK + c) * 64 + t] = S;
        ((float4*)(ws + OFF_PSUMSQ))[(b * NCHUNK + c) * 64 + t] = Q;
    }
}

// ---------- kernel 2: redundant stats finalize + distances ----------
#define RS_STEP(half)                                                   \
    {                                                                   \
        bool hi = (sub & half) != 0;                                    \
        _Pragma("unroll")                                               \
        for (int j = 0; j < half; j++) {                                \
            float send = hi ? am[j] : am[j + half];                     \
            float keep = hi ? am[j + half] : am[j];                     \
            am[j] = keep + __shfl_xor(send, half, 16);                  \
            send = hi ? as[j] : as[j + half];                           \
            keep = hi ? as[j + half] : as[j];                           \
            as[j] = keep + __shfl_xor(send, half, 16);                  \
        }                                                               \
    }

__global__ __launch_bounds__(1024) void k_dist(const float* __restrict__ means,
                                               const float* __restrict__ stds,
                                               float* __restrict__ ws) {
    __shared__ float4 lm[16 * 64], ls[16 * 64];  // [batch][64] f4 mean/std
    int tid = threadIdx.x, bid = blockIdx.x;     // 256 blocks x 1024 thr
    int lane = tid & 63, wid = tid >> 6;
    int sub = lane & 15, eg = lane >> 4;
    int e = bid * 64 + wid * 4 + eg;

    // T14: issue the big means/stds register loads FIRST so their HBM fetch
    // overlaps the psum-finalize compute below.
    const float4* mrow = (const float4*)means + (size_t)e * 64;
    const float4* srow = (const float4*)stds + (size_t)e * 64;
    float4 m[4], s[4];
#pragma unroll
    for (int k = 0; k < 4; k++) {
        m[k] = mrow[k * 16 + sub];
        s[k] = srow[k * 16 + sub];
    }

    // phase 0: redundant per-block stats finalize (deterministic, L2/L3-hot)
    {
        int b = tid >> 6, d4 = tid & 63;  // (batch, dim-quad)
        const float4* ps = (const float4*)(ws + OFF_PSUM) + (b * NCHUNK) * 64 + d4;
        const float4* pq = (const float4*)(ws + OFF_PSUMSQ) + (b * NCHUNK) * 64 + d4;
        float4 S = {0.f, 0.f, 0.f, 0.f}, Q = {0.f, 0.f, 0.f, 0.f};
#pragma unroll
        for (int c = 0; c < NCHUNK; c++) {
            float4 a = ps[c * 64], b2 = pq[c * 64];
            S.x += a.x; S.y += a.y; S.z += a.z; S.w += a.w;
            Q.x += b2.x; Q.y += b2.y; Q.z += b2.z; Q.w += b2.w;
        }
        const float inv = 1.f / NN;
        float4 M, D;
        M.x = S.x * inv; M.y = S.y * inv; M.z = S.z * inv; M.w = S.w * inv;
        D.x = sqrtf(fmaxf(Q.x * inv - M.x * M.x, 0.f));
        D.y = sqrtf(fmaxf(Q.y * inv - M.y * M.y, 0.f));
        D.z = sqrtf(fmaxf(Q.z * inv - M.z * M.z, 0.f));
        D.w = sqrtf(fmaxf(Q.w * inv - M.w * M.w, 0.f));
        lm[b * 64 + d4] = M;
        ls[b * 64 + d4] = D;
        // publish once for k_applytopk (identical values everywhere; block 0 only
        // -> saves 2MB of duplicate writes at the boundary)
        if (bid == 0) {
            ((float4*)(ws + OFF_MEANB))[b * 64 + d4] = M;
            ((float4*)(ws + OFF_STDB))[b * 64 + d4] = D;
        }
    }
    __syncthreads();

    // phase 1: distances, 64 entries per block (4 per wave)
    float am[16], as[16];
#pragma unroll
    for (int b = 0; b < 16; b++) {
        float accm = 0.f, accs = 0.f;
#pragma unroll
        for (int k = 0; k < 4; k++) {
            float4 q = lm[b * 64 + k * 16 + sub];
            float dx = m[k].x - q.x, dy = m[k].y - q.y;
            float dz = m[k].z - q.z, dw = m[k].w - q.w;
            accm += dx * dx + dy * dy + dz * dz + dw * dw;
            q = ls[b * 64 + k * 16 + sub];
            dx = s[k].x - q.x; dy = s[k].y - q.y;
            dz = s[k].z - q.z; dw = s[k].w - q.w;
            accs += dx * dx + dy * dy + dz * dz + dw * dw;
        }
        am[b] = accm; as[b] = accs;
    }
    RS_STEP(8)
    RS_STEP(4)
    RS_STEP(2)
    RS_STEP(1)
    ws[OFF_DS + sub * SZ + e] = sqrtf(am[0]) + sqrtf(as[0]);
}

// ---------- kernel 3: per-block redundant top-k/goal + apply (x prefetched) ----------
struct TkSmem {
    float wmn[16], wmx[16];
    int hist[256], hist2[256];
    float sh_lo, sh_sc;
    int sh_T, sh_below, sh_T2, sh_cnt;
    unsigned long long candK[512];
    float topd[TOPK];
    int topi[TOPK];
    float wgt[TOPK];
    float mgp[4][256], sgp[4][256];
    float shA[256], shC[256];
};

__global__ __launch_bounds__(1024) void k_applytopk(const float* __restrict__ x,
                                                    const float* __restrict__ means,
                                                    const float* __restrict__ stds,
                                                    const float* __restrict__ t1p,
                                                    const float* __restrict__ t2p,
                                                    const float* __restrict__ ws,
                                                    float* __restrict__ out) {
    __shared__ TkSmem S;
    int tid = threadIdx.x, bid = blockIdx.x;
    int batch = bid >> 4;
    int lane = tid & 63, wid = tid >> 6;
    const float4* ds4 = (const float4*)(ws + OFF_DS + batch * SZ);
    const float4* xx = (const float4*)x + (size_t)bid * 8192;

    // ds loads first, then prefetch x slice to registers (T14): x HBM fetch
    // overlaps the whole top-k phase.
    float v[16];
    float4 t0 = ds4[tid], t1_ = ds4[tid + 1024], t2_ = ds4[tid + 2048], t3 = ds4[tid + 3072];
    float4 xv[8];
#pragma unroll
    for (int i = 0; i < 8; i++) xv[i] = xx[i * 1024 + tid];
    v[0] = t0.x; v[1] = t0.y; v[2] = t0.z; v[3] = t0.w;
    v[4] = t1_.x; v[5] = t1_.y; v[6] = t1_.z; v[7] = t1_.w;
    v[8] = t2_.x; v[9] = t2_.y; v[10] = t2_.z; v[11] = t2_.w;
    v[12] = t3.x; v[13] = t3.y; v[14] = t3.z; v[15] = t3.w;

    float mn = v[0], mx = v[0];
#pragma unroll
    for (int i = 1; i < 16; i++) { mn = fminf(mn, v[i]); mx = fmaxf(mx, v[i]); }
#pragma unroll
    for (int off = 32; off > 0; off >>= 1) {
        mn = fminf(mn, __shfl_xor(mn, off, 64));
        mx = fmaxf(mx, __shfl_xor(mx, off, 64));
    }
    if (lane == 0) { S.wmn[wid] = mn; S.wmx[wid] = mx; }
    if (tid < 256) { S.hist[tid] = 0; S.hist2[tid] = 0; }
    if (tid == 0) S.sh_cnt = 0;
    __syncthreads();
    if (tid == 0) {
        float l = S.wmn[0], h = S.wmx[0];
#pragma unroll
        for (int i = 1; i < 16; i++) { l = fminf(l, S.wmn[i]); h = fmaxf(h, S.wmx[i]); }
        S.sh_lo = l;
        S.sh_sc = 255.0f / fmaxf(h - l, 1e-20f);
    }
    __syncthreads();
    float lo = S.sh_lo, sc = S.sh_sc;

    int bn[16];
#pragma unroll
    for (int i = 0; i < 16; i++) {
        bn[i] = min(max((int)((v[i] - lo) * sc), 0), 255);
        atomicAdd(&S.hist[bn[i]], 1);
    }
    __syncthreads();
    if (wid == 0) {
        int a0 = S.hist[4 * lane], a1 = S.hist[4 * lane + 1];
        int a2 = S.hist[4 * lane + 2], a3 = S.hist[4 * lane + 3];
        a1 += a0; a2 += a1; a3 += a2;
        int tot = a3, run = tot;
#pragma unroll
        for (int off = 1; off < 64; off <<= 1) {
            int o = __shfl_up(run, off, 64);
            if (lane >= off) run += o;
        }
        int excl = run - tot;
        int c0 = a0 + excl, c1 = a1 + excl, c2 = a2 + excl, c3 = a3 + excl;
        int cc[4] = {c0, c1, c2, c3};
        int pp[4] = {excl, c0, c1, c2};
#pragma unroll
        for (int j = 0; j < 4; j++)
            if (cc[j] >= TOPK && pp[j] < TOPK) { S.sh_T = 4 * lane + j; S.sh_below = pp[j]; }
    }
    __syncthreads();
    int T = S.sh_T, below = S.sh_below;

    float flo = lo + (float)T / sc;
    float fsc = sc * 255.0f;
#pragma unroll
    for (int i = 0; i < 16; i++) {
        if (bn[i] == T) {
            int fbn = min(max((int)((v[i] - flo) * fsc), 0), 255);
            atomicAdd(&S.hist2[fbn], 1);
        }
    }
    __syncthreads();
    int need = TOPK - below;
    if (wid == 0) {
        int a0 = S.hist2[4 * lane], a1 = S.hist2[4 * lane + 1];
        int a2 = S.hist2[4 * lane + 2], a3 = S.hist2[4 * lane + 3];
        a1 += a0; a2 += a1; a3 += a2;
        int tot = a3, run = tot;
#pragma unroll
        for (int off = 1; off < 64; off <<= 1) {
            int o = __shfl_up(run, off, 64);
            if (lane >= off) run += o;
        }
        int excl = run - tot;
        int c0 = a0 + excl, c1 = a1 + excl, c2 = a2 + excl, c3 = a3 + excl;
        int cc[4] = {c0, c1, c2, c3};
        int pp[4] = {excl, c0, c1, c2};
#pragma unroll
        for (int j = 0; j < 4; j++)
            if (cc[j] >= need && pp[j] < need) S.sh_T2 = 4 * lane + j;
    }
    __syncthreads();
    int T2 = S.sh_T2;

#pragma unroll
    for (int i = 0; i < 16; i++) {
        bool take = bn[i] < T;
        if (bn[i] == T) {
            int fbn = min(max((int)((v[i] - flo) * fsc), 0), 255);
            take = (fbn <= T2);
        }
        if (take) {
            int p = atomicAdd(&S.sh_cnt, 1);
            if (p < 512) {
                int idx = 4 * (tid + (i >> 2) * 1024) + (i & 3);
                S.candK[p] = ((unsigned long long)__float_as_uint(v[i]) << 32) | (unsigned int)idx;
            }
        }
    }
    __syncthreads();
    int cnt = min(S.sh_cnt, 512);

    // exact rank-count selection (rank invariant to candK fill order)
    for (int p = tid; p < cnt; p += 1024) {
        unsigned long long kp = S.candK[p];
        int rank = 0;
        for (int q = 0; q < cnt; q++) rank += (S.candK[q] < kp) ? 1 : 0;
        if (rank < TOPK) {
            S.topd[rank] = __uint_as_float((unsigned int)(kp >> 32));
            S.topi[rank] = (int)(kp & 0xffffffffu);
        }
    }
    __syncthreads();

    // softmax(exp(-t1*d)) — exact double-exponential semantics
    float t1 = t1p[0], t2v = t2p[0];
    if (wid == 0) {
        float sv = (lane < TOPK) ? expf(-t1 * S.topd[lane]) : -1e30f;
        float m = sv;
#pragma unroll
        for (int off = 32; off > 0; off >>= 1) m = fmaxf(m, __shfl_xor(m, off, 64));
        float e = (lane < TOPK) ? expf(sv - m) : 0.f;
        float sum = e;
#pragma unroll
        for (int off = 32; off > 0; off >>= 1) sum += __shfl_xor(sum, off, 64);
        if (lane < TOPK) S.wgt[lane] = e / sum;
    }
    __syncthreads();

    int d = tid & 255, qd = tid >> 8;
    float mg = 0.f, sg = 0.f;
    for (int r = qd; r < TOPK; r += 4) {
        float w = S.wgt[r];
        int idx = S.topi[r];
        mg += w * means[(size_t)idx * DIM + d];
        sg += w * stds[(size_t)idx * DIM + d];
    }
    S.mgp[qd][d] = mg; S.sgp[qd][d] = sg;
    __syncthreads();
    if (tid < 256) {
        float MG = S.mgp[0][tid] + S.mgp[1][tid] + S.mgp[2][tid] + S.mgp[3][tid];
        float SG = S.sgp[0][tid] + S.sgp[1][tid] + S.sgp[2][tid] + S.sgp[3][tid];
        float mean = ws[OFF_MEANB + batch * DIM + tid];
        float sd = ws[OFF_STDB + batch * DIM + tid];
        float lerp = 1.f / (1.f + expf(-t2v));
        float mf = lerp * MG + (1.f - lerp) * mean;
        float sf = lerp * SG + (1.f - lerp) * sd;
        float A = sf / sd;
        float C = mf - A * mean;
        S.shA[tid] = A;
        S.shC[tid] = C;
    }
    __syncthreads();

    // apply from registers (x already resident); nontemporal stores via native
    // ext_vector_type (builtin rejects HIP_vector_type float4).
    f4v* oo = (f4v*)out + (size_t)bid * 8192;
    const float4* la = (const float4*)S.shA;
    const float4* lc = (const float4*)S.shC;
#pragma unroll
    for (int i = 0; i < 8; i++) {
        int f4 = i * 1024 + tid;
        int d4 = f4 & 63;
        float4 a = la[d4], c = lc[d4];
        f4v o;
        o.x = fmaf(a.x, xv[i].x, c.x);
        o.y = fmaf(a.y, xv[i].y, c.y);
        o.z = fmaf(a.z, xv[i].z, c.z);
        o.w = fmaf(a.w, xv[i].w, c.w);
        __builtin_nontemporal_store(o, &oo[f4]);
    }
}

extern "C" void kernel_launch(void* const* d_in, const int* in_sizes, int n_in,
                              void* d_out, int out_size, void* d_ws, size_t ws_size,
                              hipStream_t stream) {
    const float* x = (const float*)d_in[0];
    const float* means = (const float*)d_in[1];
    const float* stds = (const float*)d_in[2];
    const float* t1 = (const float*)d_in[3];
    const float* t2 = (const float*)d_in[4];
    float* out = (float*)d_out;
    float* ws = (float*)d_ws;

    k_partial<<<B * NCHUNK, 512, 0, stream>>>(x, ws);
    k_dist<<<SZ / 64, 1024, 0, stream>>>(means, stds, ws);
    k_applytopk<<<256, 1024, 0, stream>>>(x, means, stds, t1, t2, ws, out);
}